// Round 3
// baseline (2744.920 us; speedup 1.0000x reference)
//
#include <hip/hip_runtime.h>

namespace {

constexpr int C     = 128;
constexpr int HF    = 116;
constexpr int WF    = 200;
constexpr int PTILE = 32;
constexpr int BLK   = 256;
constexpr int NPTS  = 200000;

__device__ __forceinline__ float red8(float v) {
  v += __shfl_down(v, 4);
  v += __shfl_down(v, 2);
  v += __shfl_down(v, 1);
  return v;   // full 8-group sum valid on lanes with (lane&7)==0
}
__device__ __forceinline__ void fma4(float4 w, float hv, float* acc) {
  acc[0] += hv * w.x; acc[1] += hv * w.y; acc[2] += hv * w.z; acc[3] += hv * w.w;
}

// ---- fused per-point pipeline (f32 in/out, weights direct from global) ----
__global__ __launch_bounds__(BLK, 2) void fuse_kernel(
    const float* __restrict__ x,       // (N,128)
    const int*   __restrict__ indices, // (N,4)
    const float* __restrict__ vox,     // (3,)
    const float* __restrict__ pcr,     // (6,)
    const float* __restrict__ trans,   // (4,3,4)
    const int*   __restrict__ imgh_p,  // scalar
    const int*   __restrict__ imgw_p,  // scalar
    const float* __restrict__ fg_w1,   // (128,64)
    const float* __restrict__ fg_b1,   // (64,)
    const float* __restrict__ fg_w2,   // (64,1)
    const float* __restrict__ fg_b2,   // (1,)
    const float* __restrict__ rt_w1,   // (131,64)
    const float* __restrict__ rt_b1,   // (64,)
    const float* __restrict__ rt_w2,   // (64,3)
    const float* __restrict__ rt_b2,   // (3,)
    const float* __restrict__ le_w1,   // (256,128)
    const float* __restrict__ le_b1,   // (128,)
    const float* __restrict__ le_w2,   // (128,128)
    const float* __restrict__ le_b2,   // (128,)
    const float* __restrict__ ln_g,    // (128,)
    const float* __restrict__ ln_b,    // (128,)
    const float* __restrict__ imgf,    // (4,128,116,200) NCHW
    float*       __restrict__ out_fused,  // (N,128)
    float*       __restrict__ out_qual)   // (N,11)
{
  __shared__ float xs[PTILE][130];    // x tile (stride 130)
  __shared__ float hs[PTILE][130];    // sampled, later hidden1
  __shared__ float s_rn[PTILE], s_pfg[PTILE], s_valid[PTILE];
  __shared__ float s_px[PTILE], s_py[PTILE], s_gain[PTILE];
  __shared__ float s_route[PTILE][3];
  __shared__ int   s_bat[PTILE];

  const int tid = threadIdx.x;
  const int n0  = blockIdx.x * PTILE;

  // ---- phase 0: load x tile (float4) + geometry ----
  {
    const float4* xsrc = (const float4*)(x + (size_t)n0 * C);
    for (int i = tid; i < PTILE * C / 4; i += BLK) {   // 1024 float4
      float4 v = xsrc[i];
      int p = i >> 5;            // 32 float4 per row
      int c = (i & 31) * 4;
      xs[p][c + 0] = v.x; xs[p][c + 1] = v.y;
      xs[p][c + 2] = v.z; xs[p][c + 3] = v.w;
    }
  }
  if (tid < PTILE) {
    int p = tid;
    int base = (n0 + p) * 4;
    int bi = indices[base + 0];
    int zi = indices[base + 1];
    int yi = indices[base + 2];
    int xi = indices[base + 3];
    float sp[3] = { (float)xi, (float)yi, (float)zi };  // reversed z,y,x -> x,y,z
    float cen[3];
#pragma unroll
    for (int k = 0; k < 3; ++k) {
      float cvs = vox[k] * 8.0f;
      cen[k] = sp[k] * cvs + pcr[k] + cvs * 0.5f;
    }
    float rn = sqrtf(cen[0] * cen[0] + cen[1] * cen[1]) / 72.0f;
    rn = fminf(fmaxf(rn, 0.0f), 1.0f);
    float pt[3];
#pragma unroll
    for (int r = 0; r < 3; ++r) {
      const float* row = trans + (bi * 3 + r) * 4;
      pt[r] = row[0] * cen[0] + row[1] * cen[1] + row[2] * cen[2] + row[3];
    }
    float depth = pt[2];
    float safe  = fmaxf(depth, 1e-5f);
    float uf = pt[0] / safe * ((float)WF / (float)imgw_p[0]);
    float vf = pt[1] / safe * ((float)HF / (float)imgh_p[0]);
    float un = 2.0f * (uf / (float)(WF - 1)) - 1.0f;
    float vn = 2.0f * (vf / (float)(HF - 1)) - 1.0f;
    bool valid = (depth > 1e-5f) && (fabsf(un) <= 1.0f) && (fabsf(vn) <= 1.0f);
    s_rn[p]    = rn;
    s_valid[p] = valid ? 1.0f : 0.0f;
    s_bat[p]   = bi;
    s_px[p]    = (un + 1.0f) * 0.5f * (float)(WF - 1);
    s_py[p]    = (vn + 1.0f) * 0.5f * (float)(HF - 1);
  }
  __syncthreads();

  const int p    = tid >> 3;   // point for MLP phases
  const int g    = tid & 7;    // 8-channel/16-channel group
  const int lane = tid & 63;
  const int lead = lane & 56;

  // ---- phase 1: fg MLP (128 -> 64 -> 1, sigmoid) ----
  {
    float acc[8];
    {
      const float4* b = (const float4*)(fg_b1 + g * 8);
      float4 b0 = b[0], b1 = b[1];
      acc[0] = b0.x; acc[1] = b0.y; acc[2] = b0.z; acc[3] = b0.w;
      acc[4] = b1.x; acc[5] = b1.y; acc[6] = b1.z; acc[7] = b1.w;
    }
    for (int i = 0; i < C; ++i) {
      float hv = xs[p][i];
      const float4* wp = (const float4*)(fg_w1 + i * 64 + g * 8);
      float4 w0 = wp[0], w1 = wp[1];
      fma4(w0, hv, acc);
      fma4(w1, hv, acc + 4);
    }
    float part = 0.0f;
#pragma unroll
    for (int j = 0; j < 8; ++j) part += fmaxf(acc[j], 0.0f) * fg_w2[g * 8 + j];
    part = red8(part);
    if (g == 0) {
      float z = part + fg_b2[0];
      s_pfg[p] = 1.0f / (1.0f + expf(-z));
    }
  }
  __syncthreads();

  // ---- phase 2: route MLP (131 -> 64 -> 3, softmax) ----
  {
    float acc[8];
    {
      const float4* b = (const float4*)(rt_b1 + g * 8);
      float4 b0 = b[0], b1 = b[1];
      acc[0] = b0.x; acc[1] = b0.y; acc[2] = b0.z; acc[3] = b0.w;
      acc[4] = b1.x; acc[5] = b1.y; acc[6] = b1.z; acc[7] = b1.w;
    }
    for (int i = 0; i < C; ++i) {
      float hv = xs[p][i];
      const float4* wp = (const float4*)(rt_w1 + i * 64 + g * 8);
      float4 w0 = wp[0], w1 = wp[1];
      fma4(w0, hv, acc);
      fma4(w1, hv, acc + 4);
    }
    float ext[3] = { s_rn[p], s_pfg[p], s_valid[p] };
#pragma unroll
    for (int e = 0; e < 3; ++e) {
      const float4* wp = (const float4*)(rt_w1 + (C + e) * 64 + g * 8);
      float4 w0 = wp[0], w1 = wp[1];
      fma4(w0, ext[e], acc);
      fma4(w1, ext[e], acc + 4);
    }
    float h[8];
#pragma unroll
    for (int j = 0; j < 8; ++j) h[j] = fmaxf(acc[j], 0.0f);
    float l[3];
#pragma unroll
    for (int k = 0; k < 3; ++k) {
      float t = 0.0f;
#pragma unroll
      for (int j = 0; j < 8; ++j) t += h[j] * rt_w2[(g * 8 + j) * 3 + k];
      l[k] = red8(t);
    }
    if (g == 0) {
      float l0 = l[0] + rt_b2[0], l1 = l[1] + rt_b2[1], l2 = l[2] + rt_b2[2];
      float m = fmaxf(l0, fmaxf(l1, l2));
      float e0 = expf(l0 - m), e1 = expf(l1 - m), e2 = expf(l2 - m);
      float inv = 1.0f / (e0 + e1 + e2);
      s_route[p][0] = e0 * inv;
      s_route[p][1] = e1 * inv;
      s_route[p][2] = e2 * inv;
    }
  }
  __syncthreads();

  // ---- phase 3: bilinear sample direct from NCHW (valid pts only) ----
  {
    int c  = tid & 127;
    int pp = tid >> 7;
    for (int p2 = pp; p2 < PTILE; p2 += 2) {
      float acc = 0.0f;
      if (s_valid[p2] > 0.5f) {
        float px = s_px[p2], py = s_py[p2];
        float x0f = floorf(px), y0f = floorf(py);
        float fx = px - x0f, fy = py - y0f;
        int ix = (int)x0f, iy = (int)y0f;
        int bb = s_bat[p2];
        const size_t base = ((size_t)bb * C + c) * (size_t)(HF * WF);
#pragma unroll
        for (int dy = 0; dy < 2; ++dy) {
#pragma unroll
          for (int dx = 0; dx < 2; ++dx) {
            int xi = ix + dx, yi = iy + dy;
            if (xi >= 0 && xi < WF && yi >= 0 && yi < HF) {
              float w = (dx ? fx : 1.0f - fx) * (dy ? fy : 1.0f - fy);
              acc += w * imgf[base + (size_t)yi * WF + xi];
            }
          }
        }
      }
      hs[p2][c] = acc;
    }
  }
  __syncthreads();

  // ---- phase 4: le layer 1 (256 -> 128, relu) ----
  const int c0 = g * 16;
  float acc1[16];
  {
    const float4* b = (const float4*)(le_b1 + c0);
#pragma unroll
    for (int q = 0; q < 4; ++q) {
      float4 bv = b[q];
      acc1[q * 4 + 0] = bv.x; acc1[q * 4 + 1] = bv.y;
      acc1[q * 4 + 2] = bv.z; acc1[q * 4 + 3] = bv.w;
    }
  }
  for (int i = 0; i < 128; ++i) {
    float hv = xs[p][i];
    const float4* wp = (const float4*)(le_w1 + i * 128 + c0);
    float4 w0 = wp[0], w1 = wp[1], w2 = wp[2], w3 = wp[3];
    fma4(w0, hv, acc1); fma4(w1, hv, acc1 + 4);
    fma4(w2, hv, acc1 + 8); fma4(w3, hv, acc1 + 12);
  }
  for (int i = 0; i < 128; ++i) {
    float hv = hs[p][i];
    const float4* wp = (const float4*)(le_w1 + (128 + i) * 128 + c0);
    float4 w0 = wp[0], w1 = wp[1], w2 = wp[2], w3 = wp[3];
    fma4(w0, hv, acc1); fma4(w1, hv, acc1 + 4);
    fma4(w2, hv, acc1 + 8); fma4(w3, hv, acc1 + 12);
  }
  __syncthreads();   // all reads of hs (sampled) done
#pragma unroll
  for (int k = 0; k < 16; ++k) hs[p][c0 + k] = fmaxf(acc1[k], 0.0f);
  __syncthreads();   // hidden1 visible to all

  // ---- phase 5: le layer 2 (128 -> 128) + delta + gain + layernorm ----
  float acc2[16];
  {
    const float4* b = (const float4*)(le_b2 + c0);
#pragma unroll
    for (int q = 0; q < 4; ++q) {
      float4 bv = b[q];
      acc2[q * 4 + 0] = bv.x; acc2[q * 4 + 1] = bv.y;
      acc2[q * 4 + 2] = bv.z; acc2[q * 4 + 3] = bv.w;
    }
  }
  for (int i = 0; i < 128; ++i) {
    float hv = hs[p][i];
    const float4* wp = (const float4*)(le_w2 + i * 128 + c0);
    float4 w0 = wp[0], w1 = wp[1], w2 = wp[2], w3 = wp[3];
    fma4(w0, hv, acc2); fma4(w1, hv, acc2 + 4);
    fma4(w2, hv, acc2 + 8); fma4(w3, hv, acc2 + 12);
  }
  {
    float rv = s_route[p][1] * s_valid[p];
    float delta[16];
#pragma unroll
    for (int k = 0; k < 16; ++k) delta[k] = acc2[k] * rv;

    float nd = 0.0f, nx = 0.0f;
#pragma unroll
    for (int k = 0; k < 16; ++k) {
      float xv = xs[p][c0 + k];
      nd += delta[k] * delta[k];
      nx += xv * xv;
    }
    nd = red8(nd); nx = red8(nx);
    nd = __shfl(nd, lead); nx = __shfl(nx, lead);
    float gain = sqrtf(nd) / (sqrtf(nx) + 1e-6f);
    gain = fminf(fmaxf(1.0f - expf(-gain), 0.0f), 1.0f);
    if (g == 0) s_gain[p] = gain;

    float y[16];
    float sum = 0.0f;
#pragma unroll
    for (int k = 0; k < 16; ++k) { y[k] = xs[p][c0 + k] + delta[k]; sum += y[k]; }
    sum = red8(sum); sum = __shfl(sum, lead);
    float mu = sum * (1.0f / 128.0f);
    float vs = 0.0f;
#pragma unroll
    for (int k = 0; k < 16; ++k) { float d = y[k] - mu; vs += d * d; }
    vs = red8(vs); vs = __shfl(vs, lead);
    float inv = rsqrtf(vs * (1.0f / 128.0f) + 1e-5f);

    float4 o[4];
    const float4* gq = (const float4*)(ln_g + c0);
    const float4* bq = (const float4*)(ln_b + c0);
#pragma unroll
    for (int q = 0; q < 4; ++q) {
      float4 gg = gq[q], bb = bq[q];
      o[q].x = (y[q * 4 + 0] - mu) * inv * gg.x + bb.x;
      o[q].y = (y[q * 4 + 1] - mu) * inv * gg.y + bb.y;
      o[q].z = (y[q * 4 + 2] - mu) * inv * gg.z + bb.z;
      o[q].w = (y[q * 4 + 3] - mu) * inv * gg.w + bb.w;
    }
    float4* dst = (float4*)(out_fused + (size_t)(n0 + p) * C + c0);
#pragma unroll
    for (int q = 0; q < 4; ++q) dst[q] = o[q];
  }
  __syncthreads();

  // ---- phase 6: quality (N,11) ----
  for (int idx = tid; idx < PTILE * 11; idx += BLK) {
    int p2 = idx / 11, k = idx - p2 * 11;
    float v = 0.0f;
    if (k < 3)       v = s_route[p2][k];
    else if (k == 3) v = s_pfg[p2];
    else if (k == 4) v = s_rn[p2];
    else if (k == 5) v = s_valid[p2];
    else if (k == 7) v = s_gain[p2];
    v = fminf(fmaxf(v, 0.0f), 1.0f);
    out_qual[(size_t)(n0 + p2) * 11 + k] = v;
  }
}

} // namespace

extern "C" void kernel_launch(void* const* d_in, const int* in_sizes, int n_in,
                              void* d_out, int out_size, void* d_ws, size_t ws_size,
                              hipStream_t stream) {
  const float* x       = (const float*)d_in[0];
  const int*   indices = (const int*)d_in[1];
  const float* vox     = (const float*)d_in[2];
  const float* pcr     = (const float*)d_in[3];
  const float* trans   = (const float*)d_in[4];
  const float* imgf    = (const float*)d_in[5];
  const int*   imgh    = (const int*)d_in[6];
  const int*   imgw    = (const int*)d_in[7];
  const float* fg_w1   = (const float*)d_in[8];
  const float* fg_b1   = (const float*)d_in[9];
  const float* fg_w2   = (const float*)d_in[10];
  const float* fg_b2   = (const float*)d_in[11];
  const float* rt_w1   = (const float*)d_in[12];
  const float* rt_b1   = (const float*)d_in[13];
  const float* rt_w2   = (const float*)d_in[14];
  const float* rt_b2   = (const float*)d_in[15];
  const float* le_w1   = (const float*)d_in[16];
  const float* le_b1   = (const float*)d_in[17];
  const float* le_w2   = (const float*)d_in[18];
  const float* le_b2   = (const float*)d_in[19];
  const float* ln_g    = (const float*)d_in[20];
  const float* ln_b    = (const float*)d_in[21];

  float* out_fused = (float*)d_out;
  float* out_qual  = out_fused + (size_t)NPTS * C;

  (void)d_ws; (void)ws_size; (void)in_sizes; (void)n_in; (void)out_size;

  fuse_kernel<<<NPTS / PTILE, BLK, 0, stream>>>(
      x, indices, vox, pcr, trans, imgh, imgw,
      fg_w1, fg_b1, fg_w2, fg_b2,
      rt_w1, rt_b1, rt_w2, rt_b2,
      le_w1, le_b1, le_w2, le_b2,
      ln_g, ln_b, imgf, out_fused, out_qual);
}

// Round 4
// 438.148 us; speedup vs baseline: 6.2648x; 6.2648x over previous
//
#include <hip/hip_runtime.h>

namespace {

typedef __attribute__((ext_vector_type(8))) short bf16x8;
typedef __attribute__((ext_vector_type(4))) float f32x4;

constexpr int C     = 128;
constexpr int HF    = 116;
constexpr int WF    = 200;
constexpr int PTILE = 32;
constexpr int BLK   = 256;
constexpr int NPTS  = 200000;
constexpr int AS_STRIDE  = 264;   // 256 + 8 shorts pad -> 2-way-free LDS banks
constexpr int HID_STRIDE = 136;   // 128 + 8

// ws layout (short offsets): packed bf16 weights in B-frag order
constexpr int W_LE1 = 0;          // 256x128 -> 32768 shorts
constexpr int W_LE2 = 32768;      // 128x128 -> 16384
constexpr int W_FG  = 49152;      // 128x64  -> 8192
constexpr int W_RT  = 57344;      // 128x64  -> 8192 (rows 0..127 of rt_w1)
constexpr size_t IMG_BYTE_OFF = 131072;   // NHWC bf16 image, 23.76 MB

__device__ __forceinline__ float b2f(unsigned short u) {
  union { unsigned int i; float f; } v; v.i = ((unsigned int)u) << 16; return v.f;
}
__device__ __forceinline__ unsigned short f2b(float f) {
  union { float f; unsigned int i; } v; v.f = f;
  unsigned int i = v.i;
  return (unsigned short)((i + 0x7fffu + ((i >> 16) & 1u)) >> 16);
}
__device__ __forceinline__ void unp(unsigned int u, float& lo, float& hi) {
  union { unsigned int i; float f; } a, b;
  a.i = u << 16; b.i = u & 0xffff0000u; lo = a.f; hi = b.f;
}
__device__ __forceinline__ unsigned int packb(float a, float b) {
  return (unsigned int)f2b(a) | ((unsigned int)f2b(b) << 16);
}

// ---- prep 1: pack weights f32 -> bf16 in B-frag order: dst[((k>>3)*N+n)*8+(k&7)] ----
__global__ __launch_bounds__(BLK) void pack_weights(
    const float* __restrict__ le_w1, const float* __restrict__ le_w2,
    const float* __restrict__ fg_w1, const float* __restrict__ rt_w1,
    short* __restrict__ wpack) {
  int idx = blockIdx.x * BLK + threadIdx.x;   // 0..65535
  if (idx < 32768) {                     // le_w1 (256,128)
    int k = idx >> 7, n = idx & 127;
    wpack[W_LE1 + (((k >> 3) * 128 + n) << 3) + (k & 7)] = (short)f2b(le_w1[idx]);
  } else if (idx < 49152) {              // le_w2 (128,128)
    int l = idx - 32768; int k = l >> 7, n = l & 127;
    wpack[W_LE2 + (((k >> 3) * 128 + n) << 3) + (k & 7)] = (short)f2b(le_w2[l]);
  } else if (idx < 57344) {              // fg_w1 (128,64)
    int l = idx - 49152; int k = l >> 6, n = l & 63;
    wpack[W_FG + (((k >> 3) * 64 + n) << 3) + (k & 7)] = (short)f2b(fg_w1[l]);
  } else {                               // rt_w1 rows 0..127 (of 131,64)
    int l = idx - 57344; int k = l >> 6, n = l & 63;
    wpack[W_RT + (((k >> 3) * 64 + n) << 3) + (k & 7)] = (short)f2b(rt_w1[k * 64 + n]);
  }
}

// ---- prep 2: img NCHW f32 -> NHWC bf16 ----
__global__ __launch_bounds__(BLK) void pack_img(const float* __restrict__ src,
                                                short* __restrict__ dst) {
  __shared__ unsigned short buf[C * 201];
  int b = blockIdx.x / HF, y = blockIdx.x % HF;
  const float* s = src + (size_t)b * C * HF * WF + (size_t)y * WF;
  for (int i = threadIdx.x; i < C * WF; i += BLK) {
    int c = i / WF, xx = i - c * WF;
    buf[c * 201 + xx] = f2b(s[(size_t)c * HF * WF + xx]);
  }
  __syncthreads();
  short* d = dst + (size_t)(b * HF + y) * WF * C;
  for (int i = threadIdx.x; i < WF * C; i += BLK) {
    int xx = i >> 7, c = i & 127;
    d[(size_t)xx * C + c] = (short)buf[c * 201 + xx];
  }
}

// ---- main fused kernel ----
__global__ __launch_bounds__(BLK, 2) void fuse_kernel(
    const float* __restrict__ x,       // (N,128)
    const int*   __restrict__ indices, // (N,4)
    const float* __restrict__ vox, const float* __restrict__ pcr,
    const float* __restrict__ trans,
    const int* __restrict__ imgh_p, const int* __restrict__ imgw_p,
    const float* __restrict__ fg_b1v, const float* __restrict__ fg_w2v,
    const float* __restrict__ fg_b2v,
    const float* __restrict__ rt_w1f,  // raw f32 (need rows 128..130)
    const float* __restrict__ rt_b1v, const float* __restrict__ rt_w2v,
    const float* __restrict__ rt_b2v,
    const float* __restrict__ le_b1v, const float* __restrict__ le_b2v,
    const float* __restrict__ ln_gv, const float* __restrict__ ln_bv,
    const short* __restrict__ wpack,   // packed bf16 weights (ws)
    const short* __restrict__ imgT,    // NHWC bf16 (ws)
    float* __restrict__ out_fused, float* __restrict__ out_qual) {
  __shared__ short As[PTILE * AS_STRIDE];     // [p][k]: x (0..127) | sampled (128..255)
  __shared__ short Hid[PTILE * HID_STRIDE];   // hidden1 bf16
  __shared__ __align__(16) short Wbuf[16384]; // 32 KB staged weights
  __shared__ float s_rn[32], s_pfg[32], s_valid[32], s_px[32], s_py[32];
  __shared__ float s_gain[32], s_rv[32];
  __shared__ float s_route[32][3];
  __shared__ int   s_bat[32];
  __shared__ __align__(16) float s_lnpart[4][16][4];

  const int tid  = threadIdx.x;
  const int n0   = blockIdx.x * PTILE;
  const int wave = tid >> 6;
  const int lane = tid & 63;
  const int q    = lane >> 4;     // quad
  const int nn   = lane & 15;

  // ================= P0: stage x -> As bf16; Wbuf <- fg|rt; geometry ==========
  {
    const float4* xsrc = (const float4*)(x + (size_t)n0 * C);
    for (int i = tid; i < PTILE * C / 4; i += BLK) {   // 1024 float4
      float4 v = xsrc[i];
      int p = i >> 5, c4 = (i & 31) * 4;
      short4 sv = { (short)f2b(v.x), (short)f2b(v.y), (short)f2b(v.z), (short)f2b(v.w) };
      *(short4*)&As[p * AS_STRIDE + c4] = sv;
    }
  }
  {
    const uint4* s1 = (const uint4*)(wpack + W_FG);    // fg + rt contiguous: 2048 uint4
    uint4* dW = (uint4*)Wbuf;
    for (int i = tid; i < 2048; i += BLK) dW[i] = s1[i];
  }
  if (tid < PTILE) {
    int p = tid;
    int base = (n0 + p) * 4;
    int bi = indices[base + 0], zi = indices[base + 1];
    int yi = indices[base + 2], xi = indices[base + 3];
    float sp[3] = { (float)xi, (float)yi, (float)zi };
    float cen[3];
#pragma unroll
    for (int k = 0; k < 3; ++k) {
      float cvs = vox[k] * 8.0f;
      cen[k] = sp[k] * cvs + pcr[k] + cvs * 0.5f;
    }
    float rn = sqrtf(cen[0] * cen[0] + cen[1] * cen[1]) / 72.0f;
    rn = fminf(fmaxf(rn, 0.0f), 1.0f);
    float pt[3];
#pragma unroll
    for (int r = 0; r < 3; ++r) {
      const float* row = trans + (bi * 3 + r) * 4;
      pt[r] = row[0] * cen[0] + row[1] * cen[1] + row[2] * cen[2] + row[3];
    }
    float depth = pt[2];
    float safe  = fmaxf(depth, 1e-5f);
    float uf = pt[0] / safe * ((float)WF / (float)imgw_p[0]);
    float vf = pt[1] / safe * ((float)HF / (float)imgh_p[0]);
    float un = 2.0f * (uf / (float)(WF - 1)) - 1.0f;
    float vn = 2.0f * (vf / (float)(HF - 1)) - 1.0f;
    bool valid = (depth > 1e-5f) && (fabsf(un) <= 1.0f) && (fabsf(vn) <= 1.0f);
    s_rn[p] = rn;
    s_valid[p] = valid ? 1.0f : 0.0f;
    s_bat[p] = bi;
    s_px[p] = (un + 1.0f) * 0.5f * (float)(WF - 1);
    s_py[p] = (vn + 1.0f) * 0.5f * (float)(HF - 1);
  }
  __syncthreads();

  // ================= P1: waves0,1 fg MFMA+epi ; waves2,3 rt x-part MFMA =======
  f32x4 accS[4];
#pragma unroll
  for (int t = 0; t < 4; ++t) accS[t] = (f32x4){0.f, 0.f, 0.f, 0.f};
  if (wave < 2) {
    const int p0 = wave * 16;
    for (int ks = 0; ks < 4; ++ks) {
      bf16x8 a = *(const bf16x8*)&As[(p0 + nn) * AS_STRIDE + ks * 32 + q * 8];
#pragma unroll
      for (int t = 0; t < 4; ++t) {
        bf16x8 b = *(const bf16x8*)&Wbuf[(((ks * 4 + q) * 64) + t * 16 + nn) * 8];
        accS[t] = __builtin_amdgcn_mfma_f32_16x16x32_bf16(a, b, accS[t], 0, 0, 0);
      }
    }
    float part[4] = {0.f, 0.f, 0.f, 0.f};
#pragma unroll
    for (int t = 0; t < 4; ++t) {
      int col = t * 16 + nn;
      float bias = fg_b1v[col];
      float w2   = fg_w2v[col];
#pragma unroll
      for (int r = 0; r < 4; ++r)
        part[r] += fmaxf(accS[t][r] + bias, 0.f) * w2;
    }
#pragma unroll
    for (int off = 1; off < 16; off <<= 1) {
#pragma unroll
      for (int r = 0; r < 4; ++r) part[r] += __shfl_xor(part[r], off);
    }
    if (nn == 0) {
      float b2 = fg_b2v[0];
#pragma unroll
      for (int r = 0; r < 4; ++r)
        s_pfg[p0 + q * 4 + r] = 1.f / (1.f + expf(-(part[r] + b2)));
    }
  } else {
    const int p0 = (wave - 2) * 16;
    for (int ks = 0; ks < 4; ++ks) {
      bf16x8 a = *(const bf16x8*)&As[(p0 + nn) * AS_STRIDE + ks * 32 + q * 8];
#pragma unroll
      for (int t = 0; t < 4; ++t) {
        bf16x8 b = *(const bf16x8*)&Wbuf[8192 + (((ks * 4 + q) * 64) + t * 16 + nn) * 8];
        accS[t] = __builtin_amdgcn_mfma_f32_16x16x32_bf16(a, b, accS[t], 0, 0, 0);
      }
    }
  }
  __syncthreads();

  // ====== P2: rt ext+epi (w2,3); Wbuf <- le_w1 half A (w0,1); sampling (all) ==
  if (wave >= 2) {
    const int p0 = (wave - 2) * 16;
    float lg0[4] = {0,0,0,0}, lg1[4] = {0,0,0,0}, lg2[4] = {0,0,0,0};
#pragma unroll
    for (int t = 0; t < 4; ++t) {
      int col = t * 16 + nn;
      float b1 = rt_b1v[col];
      float wr = rt_w1f[128 * 64 + col];
      float wp = rt_w1f[129 * 64 + col];
      float wv = rt_w1f[130 * 64 + col];
      float w20 = rt_w2v[col * 3 + 0], w21 = rt_w2v[col * 3 + 1], w22 = rt_w2v[col * 3 + 2];
#pragma unroll
      for (int r = 0; r < 4; ++r) {
        int p = p0 + q * 4 + r;
        float h = accS[t][r] + b1 + s_rn[p] * wr + s_pfg[p] * wp + s_valid[p] * wv;
        h = fmaxf(h, 0.f);
        lg0[r] += h * w20; lg1[r] += h * w21; lg2[r] += h * w22;
      }
    }
#pragma unroll
    for (int off = 1; off < 16; off <<= 1) {
#pragma unroll
      for (int r = 0; r < 4; ++r) {
        lg0[r] += __shfl_xor(lg0[r], off);
        lg1[r] += __shfl_xor(lg1[r], off);
        lg2[r] += __shfl_xor(lg2[r], off);
      }
    }
    if (nn == 0) {
      float rb0 = rt_b2v[0], rb1 = rt_b2v[1], rb2 = rt_b2v[2];
#pragma unroll
      for (int r = 0; r < 4; ++r) {
        int p = p0 + q * 4 + r;
        float l0 = lg0[r] + rb0, l1 = lg1[r] + rb1, l2 = lg2[r] + rb2;
        float m = fmaxf(l0, fmaxf(l1, l2));
        float e0 = expf(l0 - m), e1 = expf(l1 - m), e2 = expf(l2 - m);
        float inv = 1.f / (e0 + e1 + e2);
        s_route[p][0] = e0 * inv; s_route[p][1] = e1 * inv; s_route[p][2] = e2 * inv;
        s_rv[p] = e1 * inv * s_valid[p];
      }
    }
  } else {
    const uint4* s2 = (const uint4*)(wpack + W_LE1);   // rows 0..127 -> 2048 uint4
    uint4* dW = (uint4*)Wbuf;
    for (int i = tid; i < 2048; i += 128) dW[i] = s2[i];
  }
  // sampling (all threads): thread = (point, 16-ch group)
  {
    int p = tid >> 3, grp = tid & 7, ch0 = grp * 16;
    float sacc[16];
#pragma unroll
    for (int k = 0; k < 16; ++k) sacc[k] = 0.f;
    if (s_valid[p] > 0.5f) {
      float px = s_px[p], py = s_py[p];
      float x0f = floorf(px), y0f = floorf(py);
      float fx = px - x0f, fy = py - y0f;
      int ix = (int)x0f, iy = (int)y0f;
      int bb = s_bat[p];
#pragma unroll
      for (int dy = 0; dy < 2; ++dy) {
#pragma unroll
        for (int dx = 0; dx < 2; ++dx) {
          int xi = ix + dx, yi = iy + dy;
          if (xi >= 0 && xi < WF && yi >= 0 && yi < HF) {
            float w = (dx ? fx : 1.0f - fx) * (dy ? fy : 1.0f - fy);
            const short* tp = imgT + (((size_t)bb * HF + yi) * WF + xi) * C + ch0;
            uint4 u0 = *(const uint4*)tp;
            uint4 u1 = *(const uint4*)(tp + 8);
            float lo, hi;
            unp(u0.x, lo, hi); sacc[0] += w * lo;  sacc[1] += w * hi;
            unp(u0.y, lo, hi); sacc[2] += w * lo;  sacc[3] += w * hi;
            unp(u0.z, lo, hi); sacc[4] += w * lo;  sacc[5] += w * hi;
            unp(u0.w, lo, hi); sacc[6] += w * lo;  sacc[7] += w * hi;
            unp(u1.x, lo, hi); sacc[8] += w * lo;  sacc[9] += w * hi;
            unp(u1.y, lo, hi); sacc[10] += w * lo; sacc[11] += w * hi;
            unp(u1.z, lo, hi); sacc[12] += w * lo; sacc[13] += w * hi;
            unp(u1.w, lo, hi); sacc[14] += w * lo; sacc[15] += w * hi;
          }
        }
      }
    }
    uint4 o0 = { packb(sacc[0], sacc[1]),  packb(sacc[2], sacc[3]),
                 packb(sacc[4], sacc[5]),  packb(sacc[6], sacc[7]) };
    uint4 o1 = { packb(sacc[8], sacc[9]),  packb(sacc[10], sacc[11]),
                 packb(sacc[12], sacc[13]), packb(sacc[14], sacc[15]) };
    *(uint4*)&As[p * AS_STRIDE + 128 + ch0]     = o0;
    *(uint4*)&As[p * AS_STRIDE + 128 + ch0 + 8] = o1;
  }
  __syncthreads();

  // ================= P3/P4: le1 MFMA (K=256, two staged halves) ===============
  const int pt = wave & 1, cg = wave >> 1;
  const int p0le = pt * 16;
  f32x4 acc[4];
#pragma unroll
  for (int t = 0; t < 4; ++t) acc[t] = (f32x4){0.f, 0.f, 0.f, 0.f};
  for (int ks = 0; ks < 4; ++ks) {
    bf16x8 a = *(const bf16x8*)&As[(p0le + nn) * AS_STRIDE + ks * 32 + q * 8];
#pragma unroll
    for (int t = 0; t < 4; ++t) {
      bf16x8 b = *(const bf16x8*)&Wbuf[(((ks * 4 + q) * 128) + (cg * 4 + t) * 16 + nn) * 8];
      acc[t] = __builtin_amdgcn_mfma_f32_16x16x32_bf16(a, b, acc[t], 0, 0, 0);
    }
  }
  __syncthreads();
  {
    const uint4* s3 = (const uint4*)(wpack + W_LE1 + 16384);  // rows 128..255
    uint4* dW = (uint4*)Wbuf;
    for (int i = tid; i < 2048; i += BLK) dW[i] = s3[i];
  }
  __syncthreads();
  for (int ks = 0; ks < 4; ++ks) {
    bf16x8 a = *(const bf16x8*)&As[(p0le + nn) * AS_STRIDE + 128 + ks * 32 + q * 8];
#pragma unroll
    for (int t = 0; t < 4; ++t) {
      bf16x8 b = *(const bf16x8*)&Wbuf[(((ks * 4 + q) * 128) + (cg * 4 + t) * 16 + nn) * 8];
      acc[t] = __builtin_amdgcn_mfma_f32_16x16x32_bf16(a, b, acc[t], 0, 0, 0);
    }
  }
  __syncthreads();
  // epilogue: bias+relu -> Hid bf16 ; restage Wbuf <- le_w2
#pragma unroll
  for (int t = 0; t < 4; ++t) {
    int col = (cg * 4 + t) * 16 + nn;
    float bias = le_b1v[col];
#pragma unroll
    for (int r = 0; r < 4; ++r)
      Hid[(p0le + q * 4 + r) * HID_STRIDE + col] =
          (short)f2b(fmaxf(acc[t][r] + bias, 0.f));
  }
  {
    const uint4* s4 = (const uint4*)(wpack + W_LE2);
    uint4* dW = (uint4*)Wbuf;
    for (int i = tid; i < 2048; i += BLK) dW[i] = s4[i];
  }
  __syncthreads();

  // ================= P5: le2 MFMA + delta/gain/layernorm ======================
  f32x4 acc2[4];
#pragma unroll
  for (int t = 0; t < 4; ++t) acc2[t] = (f32x4){0.f, 0.f, 0.f, 0.f};
  for (int ks = 0; ks < 4; ++ks) {
    bf16x8 a = *(const bf16x8*)&Hid[(p0le + nn) * HID_STRIDE + ks * 32 + q * 8];
#pragma unroll
    for (int t = 0; t < 4; ++t) {
      bf16x8 b = *(const bf16x8*)&Wbuf[(((ks * 4 + q) * 128) + (cg * 4 + t) * 16 + nn) * 8];
      acc2[t] = __builtin_amdgcn_mfma_f32_16x16x32_bf16(a, b, acc2[t], 0, 0, 0);
    }
  }
  float yv[4][4], dv[4][4];
  float psum[4] = {0,0,0,0}, psum2[4] = {0,0,0,0}, pd2[4] = {0,0,0,0}, px2[4] = {0,0,0,0};
#pragma unroll
  for (int t = 0; t < 4; ++t) {
    int col = (cg * 4 + t) * 16 + nn;
    float bias = le_b2v[col];
#pragma unroll
    for (int r = 0; r < 4; ++r) {
      int p = p0le + q * 4 + r;
      float d  = (acc2[t][r] + bias) * s_rv[p];
      float xv = b2f((unsigned short)As[p * AS_STRIDE + col]);
      float y  = xv + d;
      yv[t][r] = y; dv[t][r] = d;
      psum[r]  += y;       psum2[r] += y * y;
      pd2[r]   += d * d;   px2[r]   += xv * xv;
    }
  }
#pragma unroll
  for (int off = 1; off < 16; off <<= 1) {
#pragma unroll
    for (int r = 0; r < 4; ++r) {
      psum[r]  += __shfl_xor(psum[r], off);
      psum2[r] += __shfl_xor(psum2[r], off);
      pd2[r]   += __shfl_xor(pd2[r], off);
      px2[r]   += __shfl_xor(px2[r], off);
    }
  }
  if (nn == 0) {
#pragma unroll
    for (int r = 0; r < 4; ++r) {
      f32x4 st = { psum[r], psum2[r], pd2[r], px2[r] };
      *(f32x4*)&s_lnpart[wave][q * 4 + r][0] = st;
    }
  }
  __syncthreads();
  {
    float gcol[4], bcol[4];
#pragma unroll
    for (int t = 0; t < 4; ++t) {
      int col = (cg * 4 + t) * 16 + nn;
      gcol[t] = ln_gv[col]; bcol[t] = ln_bv[col];
    }
#pragma unroll
    for (int r = 0; r < 4; ++r) {
      int lr = q * 4 + r;
      int p  = p0le + lr;
      f32x4 oth = *(const f32x4*)&s_lnpart[wave ^ 2][lr][0];
      float sy  = psum[r]  + oth[0];
      float sy2 = psum2[r] + oth[1];
      float sd2 = pd2[r]   + oth[2];
      float sx2 = px2[r]   + oth[3];
      float mu  = sy * (1.f / 128.f);
      float var = sy2 * (1.f / 128.f) - mu * mu;
      float inv = rsqrtf(var + 1e-5f);
      if (wave < 2 && nn == 0) {
        float gain = sqrtf(sd2) / (sqrtf(sx2) + 1e-6f);
        s_gain[p] = fminf(fmaxf(1.f - expf(-gain), 0.f), 1.f);
      }
      float* orow = out_fused + (size_t)(n0 + p) * C;
#pragma unroll
      for (int t = 0; t < 4; ++t) {
        int col = (cg * 4 + t) * 16 + nn;
        orow[col] = (yv[t][r] - mu) * inv * gcol[t] + bcol[t];
      }
    }
  }
  __syncthreads();

  // ================= P6: quality (N,11) =======================================
  for (int idx = tid; idx < PTILE * 11; idx += BLK) {
    int p2 = idx / 11, k = idx - p2 * 11;
    float v = 0.0f;
    if (k < 3)       v = s_route[p2][k];
    else if (k == 3) v = s_pfg[p2];
    else if (k == 4) v = s_rn[p2];
    else if (k == 5) v = s_valid[p2];
    else if (k == 7) v = s_gain[p2];
    v = fminf(fmaxf(v, 0.0f), 1.0f);
    out_qual[(size_t)(n0 + p2) * 11 + k] = v;
  }
}

} // namespace

extern "C" void kernel_launch(void* const* d_in, const int* in_sizes, int n_in,
                              void* d_out, int out_size, void* d_ws, size_t ws_size,
                              hipStream_t stream) {
  const float* x       = (const float*)d_in[0];
  const int*   indices = (const int*)d_in[1];
  const float* vox     = (const float*)d_in[2];
  const float* pcr     = (const float*)d_in[3];
  const float* trans   = (const float*)d_in[4];
  const float* imgf    = (const float*)d_in[5];
  const int*   imgh    = (const int*)d_in[6];
  const int*   imgw    = (const int*)d_in[7];
  const float* fg_w1   = (const float*)d_in[8];
  const float* fg_b1   = (const float*)d_in[9];
  const float* fg_w2   = (const float*)d_in[10];
  const float* fg_b2   = (const float*)d_in[11];
  const float* rt_w1   = (const float*)d_in[12];
  const float* rt_b1   = (const float*)d_in[13];
  const float* rt_w2   = (const float*)d_in[14];
  const float* rt_b2   = (const float*)d_in[15];
  const float* le_w1   = (const float*)d_in[16];
  const float* le_b1   = (const float*)d_in[17];
  const float* le_w2   = (const float*)d_in[18];
  const float* le_b2   = (const float*)d_in[19];
  const float* ln_g    = (const float*)d_in[20];
  const float* ln_b    = (const float*)d_in[21];

  short* wpack = (short*)d_ws;
  short* imgT  = (short*)((char*)d_ws + IMG_BYTE_OFF);

  float* out_fused = (float*)d_out;
  float* out_qual  = out_fused + (size_t)NPTS * C;

  (void)in_sizes; (void)n_in; (void)out_size; (void)ws_size;

  pack_weights<<<256, BLK, 0, stream>>>(le_w1, le_w2, fg_w1, rt_w1, wpack);
  pack_img<<<4 * HF, BLK, 0, stream>>>(imgf, imgT);
  fuse_kernel<<<NPTS / PTILE, BLK, 0, stream>>>(
      x, indices, vox, pcr, trans, imgh, imgw,
      fg_b1, fg_w2, fg_b2,
      rt_w1, rt_b1, rt_w2, rt_b2,
      le_b1, le_b2, ln_g, ln_b,
      wpack, imgT, out_fused, out_qual);
}